// Round 7
// baseline (233.836 us; speedup 1.0000x reference)
//
#include <hip/hip_runtime.h>

// Causal linear attention (elu+1 feature map) — per-chunk independent blocks.
// N=4, L=4096, H=12, D=M=64.  One block per 64-row chunk (3072 blocks):
//   k_chunk: A^T = Kf Qf^T (swapped: lane col = own query row), masked+packed
//            in-register (butterfly); O_loc^T = V^T Amask^T;
//            z_loc = rowsum(Amask); chunk totals S_c = V^T Kf, Ksum_c.
//            ONE barrier, no inter-chunk state, 3 LDS tiles = 27.7KB
//            -> 5 blocks/CU resident, 12 blocks/CU of work (deep pipeline:
//            some blocks' load bursts always overlap others' compute).
//   k_scanP: exclusive prefix over 64 chunk totals (batched 8-deep, L3-hot).
//   k_fix  : out = (O_loc + S_p^T Qf^T) / (z_loc + Qf.Ks_p + eps).
// Rounds 4-6 showed barrier-count/phase-structure changes are null at
// CPP>=2 (77-80us regardless); the untested lever is resident-block
// parallelism + minimal per-block serial chain.
// NOTE: no __launch_bounds__ min-waves arg anywhere — rounds 2/3 proved it
// forces VGPR=64 and spills (~+80MB scratch writes, 2x slowdown).

#define NBATCH 4
#define LSEQ   4096
#define NHEAD  12
#define DDIM   64
#define LSTRIDE (NHEAD * DDIM)
#define NH     (NBATCH * NHEAD)
#define EPSF   1e-6f
#define CHUNK  64
#define NUMC   (LSEQ / CHUNK)   // 64 chunks = 64 scan partitions
#define SB     72               // LDS row stride in shorts (16B-aligned frags)

typedef __attribute__((ext_vector_type(8))) short bf16x8;
typedef __attribute__((ext_vector_type(4))) float f32x4;

__device__ __forceinline__ float phi(float x) { return x > 0.f ? x + 1.f : __expf(x); }
__device__ __forceinline__ float4 phi4(float4 x) {
    float4 r = {phi(x.x), phi(x.y), phi(x.z), phi(x.w)};
    return r;
}

__device__ __forceinline__ unsigned short f2bf(float x) {
    union { float f; unsigned u; } v; v.f = x;
    unsigned r = v.u + 0x7fffu + ((v.u >> 16) & 1u);   // RNE
    return (unsigned short)(r >> 16);
}
__device__ __forceinline__ float bf2f(short s) {
    union { float f; unsigned u; } v; v.u = ((unsigned)(unsigned short)s) << 16;
    return v.f;
}
__device__ __forceinline__ uint2 pack4(float4 a) {
    uint2 r;
    r.x = (unsigned)f2bf(a.x) | ((unsigned)f2bf(a.y) << 16);
    r.y = (unsigned)f2bf(a.z) | ((unsigned)f2bf(a.w) << 16);
    return r;
}
__device__ __forceinline__ bf16x8 packbf8(float4 a, float4 b) {
    union { bf16x8 v; uint2 u[2]; } r;
    r.u[0] = pack4(a);
    r.u[1] = pack4(b);
    return r.v;
}

// 4x4 fp32 transpose among lanes {lane^16, lane^32}.
__device__ __forceinline__ float4 xpose4(float4 x, int lane) {
    const bool b0 = (lane >> 4) & 1, b1 = (lane >> 5) & 1;
    float s0 = b0 ? x.x : x.y;
    float s1 = b0 ? x.z : x.w;
    s0 = __shfl_xor(s0, 16);
    s1 = __shfl_xor(s1, 16);
    float4 y;
    if (b0) { y.x = s0;  y.y = x.y; y.z = s1;  y.w = x.w; }
    else    { y.x = x.x; y.y = s0;  y.z = x.z; y.w = s1;  }
    float t0 = b1 ? y.x : y.z;
    float t1 = b1 ? y.y : y.w;
    t0 = __shfl_xor(t0, 32);
    t1 = __shfl_xor(t1, 32);
    float4 z;
    if (b1) { z.x = t0;  z.y = t1;  z.z = y.z; z.w = y.w; }
    else    { z.x = y.x; z.y = y.y; z.z = t0;  z.w = t1;  }
    return z;
}

// Exchange one lane-bit (mask m: 16 or 32) with the reg-bit distinguishing
// A/B: element at (laneBit, reg) moves to (reg, laneBit).  8B payload.
__device__ __forceinline__ void swapbit(uint2& A, uint2& B, int m, bool hi) {
    uint2 t;
    t.x = hi ? A.x : B.x;
    t.y = hi ? A.y : B.y;
    t.x = (unsigned)__shfl_xor((int)t.x, m);
    t.y = (unsigned)__shfl_xor((int)t.y, m);
    if (hi) { A.x = t.x; A.y = t.y; } else { B.x = t.x; B.y = t.y; }
}

// ---------------------------------------------------------------------------
// Kernel 1: one 64-row chunk per block.  Fully independent, one barrier.
// Writes unnormalized O_loc (O^T frags -> float4) + z_loc, publishes chunk
// totals (S_c = V^T Kf, Ksum_c).
// ---------------------------------------------------------------------------
__global__ __launch_bounds__(256) void k_chunk(const float* __restrict__ qin,
                                               const float* __restrict__ kin,
                                               const float* __restrict__ vin,
                                               float* __restrict__ kvws,
                                               float* __restrict__ ksws,
                                               float* __restrict__ zws,
                                               float* __restrict__ out) {
    __shared__ short sK [64 * SB];   // Kf rows [l][d]
    __shared__ short sKT[64 * SB];   // Kf^T    [d][l]
    __shared__ short sVT[64 * SB];   // V^T     [m][l]

    const int b = blockIdx.x, seq = b / NUMC, c = b % NUMC;
    const int n0 = seq / NHEAD, h0 = seq % NHEAD;
    const int t = threadIdx.x;
    const int lane = t & 63, w = t >> 6;
    const int nn = lane & 15, qq = lane >> 4;
    const int c4 = nn << 2;
    const bool b4 = (lane >> 4) & 1, b5 = (lane >> 5) & 1;
    const int gbase = ((n0 * LSEQ + c * CHUNK) * NHEAD + h0) * DDIM;
    const int iRow = 16 * w + nn;    // this lane's query row / V^T band row

    // ---- issue all global loads up-front ----
    float4 kreg[4], vreg[4];
#pragma unroll
    for (int rep = 0; rep < 4; ++rep) {
        const int r16 = rep * 16 + 4 * w + qq;
        kreg[rep] = *(const float4*)(kin + gbase + r16 * LSTRIDE + c4);
        vreg[rep] = *(const float4*)(vin + gbase + r16 * LSTRIDE + c4);
    }
    const float* qp = qin + gbase + iRow * LSTRIDE;
    float4 qa = *(const float4*)(qp + qq * 8);
    float4 qb = *(const float4*)(qp + qq * 8 + 4);
    float4 qc = *(const float4*)(qp + 32 + qq * 8);
    float4 qd = *(const float4*)(qp + 32 + qq * 8 + 4);
    const bf16x8 qf0 = packbf8(phi4(qa), phi4(qb));
    const bf16x8 qf1 = packbf8(phi4(qc), phi4(qd));

    // ---- stage chunk into LDS (K rows + K^T + V^T) ----
#pragma unroll
    for (int rep = 0; rep < 4; ++rep) {
        const int row = rep * 16 + 4 * w + qq;
        const int l0 = rep * 16 + 4 * w;
        float4 kp = phi4(kreg[rep]);
        *(uint2*)(sK + row * SB + c4) = pack4(kp);
        float4 kt = xpose4(kp, lane);
        *(uint2*)(sKT + (c4 + qq) * SB + l0) = pack4(kt);
        float4 vt = xpose4(vreg[rep], lane);
        *(uint2*)(sVT + (c4 + qq) * SB + l0) = pack4(vt);
    }
    __syncthreads();   // the only barrier

    // ---- Phase A (swapped): A^T[l][i] = mfma(Kf, Qf); lane col = iRow ----
    uint2 W[4];
    float zpart = 0.f;
#pragma unroll
    for (int ct = 0; ct < 4; ++ct) {
        bf16x8 kf0 = *(const bf16x8*)(sK + (16 * ct + nn) * SB + qq * 8);
        bf16x8 kf1 = *(const bf16x8*)(sK + (16 * ct + nn) * SB + 32 + qq * 8);
        f32x4 acc = {0.f, 0.f, 0.f, 0.f};
        acc = __builtin_amdgcn_mfma_f32_16x16x32_bf16(kf0, qf0, acc, 0, 0, 0);
        acc = __builtin_amdgcn_mfma_f32_16x16x32_bf16(kf1, qf1, acc, 0, 0, 0);
        float4 mv;
        mv.x = (16 * ct + 4 * qq + 0 <= iRow) ? acc[0] : 0.f;
        mv.y = (16 * ct + 4 * qq + 1 <= iRow) ? acc[1] : 0.f;
        mv.z = (16 * ct + 4 * qq + 2 <= iRow) ? acc[2] : 0.f;
        mv.w = (16 * ct + 4 * qq + 3 <= iRow) ? acc[3] : 0.f;
        zpart += mv.x + mv.y + mv.z + mv.w;
        W[ct] = pack4(mv);
    }
    zpart += __shfl_xor(zpart, 16);
    zpart += __shfl_xor(zpart, 32);
    const float zi = zpart;          // z_loc for row iRow (lane-local)

    // ---- butterfly: C-frag -> AV B-operand layout ----
    swapbit(W[0], W[1], 32, b5);
    swapbit(W[2], W[3], 32, b5);
    swapbit(W[0], W[1], 16, b4);
    swapbit(W[2], W[3], 16, b4);
    union U8 { unsigned u[4]; bf16x8 v; };
    U8 a0, a1;
    a0.u[0] = W[0].x; a0.u[1] = W[0].y; a0.u[2] = W[1].x; a0.u[3] = W[1].y;
    a1.u[0] = W[2].x; a1.u[1] = W[2].y; a1.u[2] = W[3].x; a1.u[3] = W[3].y;
    const bf16x8 amB0 = a0.v;
    const bf16x8 amB1 = a1.v;

    // ---- Phase B: O^T = V^T Amask^T ; chunk totals S_c = V^T Kf, Ksum_c ----
    f32x4 o[4]    = {{0,0,0,0},{0,0,0,0},{0,0,0,0},{0,0,0,0}};
    f32x4 Sreg[4] = {{0,0,0,0},{0,0,0,0},{0,0,0,0},{0,0,0,0}};
    bf16x8 av0 = *(const bf16x8*)(sVT + iRow * SB + qq * 8);
    bf16x8 av1 = *(const bf16x8*)(sVT + iRow * SB + 32 + qq * 8);
    float ksc = 0.f;
#pragma unroll
    for (int ct = 0; ct < 4; ++ct) {
        bf16x8 vf0 = *(const bf16x8*)(sVT + (16 * ct + nn) * SB + qq * 8);
        bf16x8 vf1 = *(const bf16x8*)(sVT + (16 * ct + nn) * SB + 32 + qq * 8);
        o[ct] = __builtin_amdgcn_mfma_f32_16x16x32_bf16(vf0, amB0, o[ct], 0, 0, 0);
        o[ct] = __builtin_amdgcn_mfma_f32_16x16x32_bf16(vf1, amB1, o[ct], 0, 0, 0);
        bf16x8 kt0 = *(const bf16x8*)(sKT + (16 * ct + nn) * SB + qq * 8);
        bf16x8 kt1 = *(const bf16x8*)(sKT + (16 * ct + nn) * SB + 32 + qq * 8);
        Sreg[ct] = __builtin_amdgcn_mfma_f32_16x16x32_bf16(av0, kt0, Sreg[ct], 0, 0, 0);
        Sreg[ct] = __builtin_amdgcn_mfma_f32_16x16x32_bf16(av1, kt1, Sreg[ct], 0, 0, 0);
        if (ct == w) {   // chunk Ksum for d-band 16w..16w+15 (d = 16w+nn)
            float s = 0.f;
#pragma unroll
            for (int j = 0; j < 8; ++j) s += bf2f(kt0[j]) + bf2f(kt1[j]);
            s += __shfl_xor(s, 16);
            s += __shfl_xor(s, 32);
            ksc = s;
        }
    }

    // ---- write unnormalized O_loc (float4 per ct) + z_loc ----
    float* orow = out + gbase + iRow * LSTRIDE;
#pragma unroll
    for (int ct = 0; ct < 4; ++ct)
        *(f32x4*)(orow + 16 * ct + 4 * qq) = o[ct];
    if (qq == 0)
        zws[seq * LSEQ + c * CHUNK + iRow] = zi;

    // ---- publish chunk totals ----
    float* kvb = kvws + (size_t)b * (DDIM * DDIM);
#pragma unroll
    for (int ct = 0; ct < 4; ++ct)
#pragma unroll
        for (int r = 0; r < 4; ++r)
            kvb[(16 * w + 4 * qq + r) * DDIM + 16 * ct + nn] = Sreg[ct][r];
    if (qq == 0) ksws[b * DDIM + 16 * w + nn] = ksc;
}

// ---------------------------------------------------------------------------
// Kernel 2: exclusive prefix scan over 64 chunk totals, batched register
// loads (8 in flight) so HBM/L3 latency is paid 8x per thread, not 64x.
// ---------------------------------------------------------------------------
__global__ __launch_bounds__(64) void k_scanP(float* __restrict__ kv,
                                              float* __restrict__ ksum) {
    const int bid = blockIdx.x;
    const int seq = bid >> 4, part16 = bid & 15;
    const int t = threadIdx.x;
    float4* base = (float4*)(kv + (size_t)seq * NUMC * DDIM * DDIM) + part16 * 64 + t;
    float4 S = {0.f, 0.f, 0.f, 0.f};
    for (int b0 = 0; b0 < NUMC; b0 += 8) {
        float4 x[8];
#pragma unroll
        for (int j = 0; j < 8; ++j) x[j] = base[(b0 + j) * (DDIM * DDIM / 4)];
#pragma unroll
        for (int j = 0; j < 8; ++j) {
            base[(b0 + j) * (DDIM * DDIM / 4)] = S;
            S.x += x[j].x; S.y += x[j].y; S.z += x[j].z; S.w += x[j].w;
        }
    }
    if (part16 == 0) {
        float* kb = ksum + (size_t)seq * NUMC * DDIM + t;
        float s = 0.f;
        for (int b0 = 0; b0 < NUMC; b0 += 8) {
            float xs[8];
#pragma unroll
            for (int j = 0; j < 8; ++j) xs[j] = kb[(b0 + j) * DDIM];
#pragma unroll
            for (int j = 0; j < 8; ++j) { kb[(b0 + j) * DDIM] = s; s += xs[j]; }
        }
    }
}

// ---------------------------------------------------------------------------
// Kernel 3: streaming fixup, one block per chunk (swapped layout):
//   out = (O_loc + S_p^T Qf^T) / (z_loc + Qf.Ks_p + eps)
// O_loc round-trips as float4; z lane-local; 1 barrier.  S_p/Ks_p are the
// freshly-scanned chunk prefixes (L3-hot).  c==0 skips the S_p work.
// ---------------------------------------------------------------------------
__global__ __launch_bounds__(256) void k_fix(const float* __restrict__ qin,
                                             const float* __restrict__ kvws,
                                             const float* __restrict__ ksws,
                                             const float* __restrict__ zws,
                                             float* __restrict__ out) {
    __shared__ short sST[64 * SB];   // bf16 S_p^T ([m][d] rows)
    __shared__ float sKs[64];

    const int cg = blockIdx.x;
    const int seq = cg / NUMC, c = cg % NUMC;
    const int n0 = seq / NHEAD, h0 = seq % NHEAD;
    const int t = threadIdx.x;
    const int lane = t & 63, w = t >> 6;
    const int nn = lane & 15, qq = lane >> 4;
    const int c4 = nn << 2;
    const int gbase = ((n0 * LSEQ + c * CHUNK) * NHEAD + h0) * DDIM;
    const int iRow = 16 * w + nn;

    if (t < 64) sKs[t] = ksws[(size_t)cg * DDIM + t];

    // S_p rows -> bf16 LDS
    const float* Sg = kvws + (size_t)cg * (DDIM * DDIM);
#pragma unroll
    for (int rep = 0; rep < 4; ++rep) {
        const int row = rep * 16 + 4 * w + qq;
        float4 sv = *(const float4*)(Sg + row * DDIM + c4);
        *(uint2*)(sST + row * SB + c4) = pack4(sv);
    }

    // Qf rows (direct, same phi+pack as pass1)
    const float* qp = qin + gbase + iRow * LSTRIDE;
    float4 a  = phi4(*(const float4*)(qp + qq * 8));
    float4 bq = phi4(*(const float4*)(qp + qq * 8 + 4));
    float4 cq = phi4(*(const float4*)(qp + 32 + qq * 8));
    float4 dq = phi4(*(const float4*)(qp + 32 + qq * 8 + 4));
    bf16x8 qf0 = packbf8(a, bq);
    bf16x8 qf1 = packbf8(cq, dq);

    // O_loc (O^T fragments, float4) + z_loc (lane-local)
    float* orow = out + gbase + iRow * LSTRIDE;
    f32x4 o[4];
#pragma unroll
    for (int ct = 0; ct < 4; ++ct)
        o[ct] = *(const f32x4*)(orow + 16 * ct + 4 * qq);
    const float zl = zws[seq * LSEQ + c * CHUNK + iRow];
    __syncthreads();   // sST + sKs ready

    // zq = Qf . Ks_p for row iRow (lane-local after reduce)
    float zq = 0.f;
#pragma unroll
    for (int j = 0; j < 8; ++j) {
        zq += bf2f(qf0[j]) * sKs[qq * 8 + j];
        zq += bf2f(qf1[j]) * sKs[32 + qq * 8 + j];
    }
    zq += __shfl_xor(zq, 16);
    zq += __shfl_xor(zq, 32);

    // o += S_p^T Qf^T  (A = S^T rows m, B = Qf)
#pragma unroll
    for (int ct = 0; ct < 4; ++ct) {
        bf16x8 sf0 = *(const bf16x8*)(sST + (16 * ct + nn) * SB + qq * 8);
        bf16x8 sf1 = *(const bf16x8*)(sST + (16 * ct + nn) * SB + 32 + qq * 8);
        o[ct] = __builtin_amdgcn_mfma_f32_16x16x32_bf16(sf0, qf0, o[ct], 0, 0, 0);
        o[ct] = __builtin_amdgcn_mfma_f32_16x16x32_bf16(sf1, qf1, o[ct], 0, 0, 0);
    }

    const float invz = 1.f / (zl + zq + EPSF);
#pragma unroll
    for (int ct = 0; ct < 4; ++ct) {
        f32x4 r = o[ct];
        r[0] *= invz; r[1] *= invz; r[2] *= invz; r[3] *= invz;
        *(f32x4*)(orow + 16 * ct + 4 * qq) = r;
    }
}

// ---------------------------------------------------------------------------
// Fallback (tiny ws): fully sequential per-sequence scan, fp32, no workspace.
// ---------------------------------------------------------------------------
__global__ __launch_bounds__(64) void k_seq(const float* __restrict__ qin,
                                            const float* __restrict__ kin,
                                            const float* __restrict__ vin,
                                            float* __restrict__ out) {
    const int seq = blockIdx.x;
    const int n = seq / NHEAD, h = seq % NHEAD;
    const int lane = threadIdx.x;
    float Scol[DDIM];
#pragma unroll
    for (int d = 0; d < DDIM; ++d) Scol[d] = 0.0f;
    float kc = 0.0f;
    __shared__ float qk[2 * DDIM];
    int base = (n * LSEQ * NHEAD + h) * DDIM + lane;
    for (int i = 0; i < LSEQ; ++i) {
        float qval = phi(qin[base]);
        float kval = phi(kin[base]);
        float vval = vin[base];
        kc += kval;
        float zp = qval * kc;
#pragma unroll
        for (int off = 32; off > 0; off >>= 1) zp += __shfl_xor(zp, off, 64);
        float z = zp + EPSF;
        qk[2 * lane] = kval;
        qk[2 * lane + 1] = qval;
        __syncthreads();
        const float4* qk4 = (const float4*)qk;
        float acc = 0.0f;
#pragma unroll
        for (int d2 = 0; d2 < DDIM / 2; ++d2) {
            float4 t0 = qk4[d2];
            int d = 2 * d2;
            Scol[d]     += t0.x * vval;  acc += t0.y * Scol[d];
            Scol[d + 1] += t0.z * vval;  acc += t0.w * Scol[d + 1];
        }
        out[base] = acc / z;
        base += LSTRIDE;
        __syncthreads();
    }
}

// ---------------------------------------------------------------------------
extern "C" void kernel_launch(void* const* d_in, const int* in_sizes, int n_in,
                              void* d_out, int out_size, void* d_ws, size_t ws_size,
                              hipStream_t stream) {
    const float* q = (const float*)d_in[0];
    const float* k = (const float*)d_in[1];
    const float* v = (const float*)d_in[2];
    float* out = (float*)d_out;
    float* ws  = (float*)d_ws;

    const size_t need = ((size_t)NH * NUMC * (DDIM * DDIM + DDIM)
                        + (size_t)NH * LSEQ) * sizeof(float);
    if (ws_size >= need) {
        float* kv   = ws;
        float* ksum = kv + (size_t)NH * NUMC * DDIM * DDIM;
        float* zws  = ksum + (size_t)NH * NUMC * DDIM;
        k_chunk<<<NH * NUMC, 256, 0, stream>>>(q, k, v, kv, ksum, zws, out);
        k_scanP<<<NH * 16,    64, 0, stream>>>(kv, ksum);
        k_fix  <<<NH * NUMC, 256, 0, stream>>>(q, kv, ksum, zws, out);
    } else {
        k_seq<<<NH, 64, 0, stream>>>(q, k, v, out);
    }
}

// Round 8
// 203.168 us; speedup vs baseline: 1.1509x; 1.1509x over previous
//
#include <hip/hip_runtime.h>

// Causal linear attention (elu+1 feature map) — best-measured topology
// (round-1: psum -> scan -> fused) + swapped-MFMA fused body + v_cvt_pk
// bf16 packing.  N=4, L=4096, H=12, D=M=64.  16 partitions x 4 chunks.
//   k_psum : per-partition KV^T total (fp32 MFMA over 4 chunks) + Ksum.
//   k_scanP: exclusive prefix scan over 16 partitions (tiny).
//   k_fused: walks the partition's 4 chunks with prefix S (bf16 mirror in
//            LDS, fp32 in regs):  A^T = Kf Qf^T (swapped: lane col = own
//            query row) -> mask+pack in-register (butterfly);
//            O^T = V^T Amask^T + S^T Qf^T;  z = rowsum + Qf.Ksum (lane-local);
//            S += KV^T(chunk).  2 barriers/chunk, float4 out stores.
// Learned constraints honored:
//  - NO __launch_bounds__ min-waves arg (forces VGPR=64 -> spills, r2/r3).
//  - fused runs AFTER psum so its q/k/v reads are L2/L3-warm (r1 vs r4-7:
//    staging kernels are ~2.8 TB/s cold but ~4+ TB/s warm).
//  - single final out write (no unnormalized round-trip — r4-7 regression).
//  - v_cvt_pk_bf16_f32 (1 op / 2 elems) replaces hand-rolled RNE f2bf
//    (~5 ops/elem) in all hot packing paths.

#define NBATCH 4
#define LSEQ   4096
#define NHEAD  12
#define DDIM   64
#define LSTRIDE (NHEAD * DDIM)
#define NH     (NBATCH * NHEAD)
#define EPSF   1e-6f
#define CHUNK  64
#define NUMC   (LSEQ / CHUNK)
#define PPART  16               // partitions per sequence
#define CPP    (NUMC / PPART)   // chunks per partition = 4
#define SB     72               // LDS row stride in shorts (16B-aligned frags)

typedef __attribute__((ext_vector_type(8))) short bf16x8;
typedef __attribute__((ext_vector_type(4))) float f32x4;

__device__ __forceinline__ float phi(float x) { return x > 0.f ? x + 1.f : __expf(x); }
__device__ __forceinline__ float4 phi4(float4 x) {
    float4 r = {phi(x.x), phi(x.y), phi(x.z), phi(x.w)};
    return r;
}

// fp32 pair -> packed bf16x2 (RNE), single VALU op on gfx950.
__device__ __forceinline__ unsigned cvt2(float lo, float hi) {
    unsigned r;
    asm("v_cvt_pk_bf16_f32 %0, %1, %2" : "=v"(r) : "v"(lo), "v"(hi));
    return r;
}
__device__ __forceinline__ unsigned short f2bf(float x) {   // scalar fallback (RNE)
    union { float f; unsigned u; } v; v.f = x;
    unsigned r = v.u + 0x7fffu + ((v.u >> 16) & 1u);
    return (unsigned short)(r >> 16);
}
__device__ __forceinline__ float bf2f(short s) {
    union { float f; unsigned u; } v; v.u = ((unsigned)(unsigned short)s) << 16;
    return v.f;
}
__device__ __forceinline__ uint2 pack4(float4 a) {
    uint2 r;
    r.x = cvt2(a.x, a.y);
    r.y = cvt2(a.z, a.w);
    return r;
}
__device__ __forceinline__ bf16x8 packbf8(float4 a, float4 b) {
    union { bf16x8 v; uint2 u[2]; } r;
    r.u[0] = pack4(a);
    r.u[1] = pack4(b);
    return r.v;
}

// 4x4 fp32 transpose among lanes {lane^16, lane^32}.
__device__ __forceinline__ float4 xpose4(float4 x, int lane) {
    const bool b0 = (lane >> 4) & 1, b1 = (lane >> 5) & 1;
    float s0 = b0 ? x.x : x.y;
    float s1 = b0 ? x.z : x.w;
    s0 = __shfl_xor(s0, 16);
    s1 = __shfl_xor(s1, 16);
    float4 y;
    if (b0) { y.x = s0;  y.y = x.y; y.z = s1;  y.w = x.w; }
    else    { y.x = x.x; y.y = s0;  y.z = x.z; y.w = s1;  }
    float t0 = b1 ? y.x : y.z;
    float t1 = b1 ? y.y : y.w;
    t0 = __shfl_xor(t0, 32);
    t1 = __shfl_xor(t1, 32);
    float4 z;
    if (b1) { z.x = t0;  z.y = t1;  z.z = y.z; z.w = y.w; }
    else    { z.x = y.x; z.y = y.y; z.z = t0;  z.w = t1;  }
    return z;
}

// Exchange one lane-bit (mask m: 16 or 32) with the reg-bit distinguishing
// A/B: element at (laneBit, reg) moves to (reg, laneBit).  8B payload.
__device__ __forceinline__ void swapbit(uint2& A, uint2& B, int m, bool hi) {
    uint2 t;
    t.x = hi ? A.x : B.x;
    t.y = hi ? A.y : B.y;
    t.x = (unsigned)__shfl_xor((int)t.x, m);
    t.y = (unsigned)__shfl_xor((int)t.y, m);
    if (hi) { A.x = t.x; A.y = t.y; } else { B.x = t.x; B.y = t.y; }
}

// ---------------------------------------------------------------------------
// Kernel 1: partition totals.  KV^T[m][d] = sum_l V[l][m] Kf[l][d] over 256
// rows (4 sub-chunks, fp32 MFMA accumulation), Ksum[d] = sum_l Kf[l][d].
// 2 LDS tiles = 18.4KB -> 8 blocks/CU.
// ---------------------------------------------------------------------------
__global__ __launch_bounds__(256) void k_psum(const float* __restrict__ kin,
                                              const float* __restrict__ vin,
                                              float* __restrict__ kvws,
                                              float* __restrict__ ksws) {
    __shared__ short sKT[64 * SB];   // [d][l]
    __shared__ short sVT[64 * SB];   // [m][l]
    const int b = blockIdx.x, seq = b / PPART, p = b % PPART;
    const int n0 = seq / NHEAD, h0 = seq % NHEAD;
    const int t = threadIdx.x;
    const int lane = t & 63, w = t >> 6;
    const int nn = lane & 15, qq = lane >> 4;
    const int c4 = nn << 2;

    float4 kreg[4], vreg[4];
    auto LOADKV = [&](int cc) {
        const int gb = ((n0 * LSEQ + (p * CPP + cc) * CHUNK) * NHEAD + h0) * DDIM;
#pragma unroll
        for (int rep = 0; rep < 4; ++rep) {
            const int r16 = rep * 16 + 4 * w + qq;
            kreg[rep] = *(const float4*)(kin + gb + r16 * LSTRIDE + c4);
            vreg[rep] = *(const float4*)(vin + gb + r16 * LSTRIDE + c4);
        }
    };

    f32x4 S[4] = {{0,0,0,0},{0,0,0,0},{0,0,0,0},{0,0,0,0}};
    float ks = 0.f;
    LOADKV(0);
    for (int cc = 0; cc < CPP; ++cc) {
#pragma unroll
        for (int rep = 0; rep < 4; ++rep) {
            const int l0 = rep * 16 + 4 * w;
            float4 kp = phi4(kreg[rep]);
            float4 kt = xpose4(kp, lane);
            *(uint2*)(sKT + (c4 + qq) * SB + l0) = pack4(kt);
            float4 vt = xpose4(vreg[rep], lane);
            *(uint2*)(sVT + (c4 + qq) * SB + l0) = pack4(vt);
        }
        __syncthreads();
        if (cc + 1 < CPP) LOADKV(cc + 1);   // latency hides under MFMA
        const int rowM = 16 * w + nn;
        bf16x8 af0 = *(const bf16x8*)(sVT + rowM * SB + qq * 8);
        bf16x8 af1 = *(const bf16x8*)(sVT + rowM * SB + 32 + qq * 8);
#pragma unroll
        for (int ct = 0; ct < 4; ++ct) {
            bf16x8 bf0 = *(const bf16x8*)(sKT + (16 * ct + nn) * SB + qq * 8);
            bf16x8 bf1 = *(const bf16x8*)(sKT + (16 * ct + nn) * SB + 32 + qq * 8);
            S[ct] = __builtin_amdgcn_mfma_f32_16x16x32_bf16(af0, bf0, S[ct], 0, 0, 0);
            S[ct] = __builtin_amdgcn_mfma_f32_16x16x32_bf16(af1, bf1, S[ct], 0, 0, 0);
            if (ct == w) {   // wave-uniform: Ksum for d-band 16w..16w+15
                float s = 0.f;
#pragma unroll
                for (int j = 0; j < 8; ++j) s += bf2f(bf0[j]) + bf2f(bf1[j]);
                s += __shfl_xor(s, 16);
                s += __shfl_xor(s, 32);
                ks += s;
            }
        }
        __syncthreads();
    }
    float* kvb = kvws + (size_t)b * (DDIM * DDIM);
#pragma unroll
    for (int ct = 0; ct < 4; ++ct)
#pragma unroll
        for (int r = 0; r < 4; ++r)
            kvb[(16 * w + 4 * qq + r) * DDIM + 16 * ct + nn] = S[ct][r];
    if (qq == 0) ksws[b * DDIM + 16 * w + nn] = ks;
}

// ---------------------------------------------------------------------------
// Kernel 2: exclusive prefix scan over the 16 partitions (loads fully
// unrolled up-front so HBM latency is paid once).
// ---------------------------------------------------------------------------
__global__ __launch_bounds__(64) void k_scanP(float* __restrict__ kv,
                                              float* __restrict__ ksum) {
    const int bid = blockIdx.x;
    const int seq = bid >> 4, part = bid & 15;
    const int t = threadIdx.x;
    float4* base = (float4*)(kv + (size_t)seq * PPART * DDIM * DDIM) + part * 64 + t;
    float4 x[PPART];
#pragma unroll
    for (int c = 0; c < PPART; ++c) x[c] = base[c * (DDIM * DDIM / 4)];
    float4 S = {0.f, 0.f, 0.f, 0.f};
#pragma unroll
    for (int c = 0; c < PPART; ++c) {
        base[c * (DDIM * DDIM / 4)] = S;
        S.x += x[c].x; S.y += x[c].y; S.z += x[c].z; S.w += x[c].w;
    }
    if (part == 0) {
        float* kb = ksum + (size_t)seq * PPART * DDIM + t;
        float xs[PPART];
#pragma unroll
        for (int c = 0; c < PPART; ++c) xs[c] = kb[c * DDIM];
        float s = 0.f;
#pragma unroll
        for (int c = 0; c < PPART; ++c) { kb[c * DDIM] = s; s += xs[c]; }
    }
}

// ---------------------------------------------------------------------------
// Kernel 3: fused per-partition output (swapped MFMA).  Walks 4 chunks with
// prefix S (fp32 regs + bf16 LDS mirror); writes final normalized out once.
// 4 LDS tiles = 36.9KB -> 4 blocks/CU.  Runs warm (after psum).
// ---------------------------------------------------------------------------
__global__ __launch_bounds__(256) void k_fused(const float* __restrict__ qin,
                                               const float* __restrict__ kin,
                                               const float* __restrict__ vin,
                                               const float* __restrict__ kvws,
                                               const float* __restrict__ ksws,
                                               float* __restrict__ out) {
    __shared__ short sK [64 * SB];   // Kf rows [l][d]
    __shared__ short sKT[64 * SB];   // Kf^T    [d][l]
    __shared__ short sVT[64 * SB];   // V^T     [m][l]
    __shared__ short sST[64 * SB];   // bf16 mirror of running S^T [m][d]
    __shared__ float sKs[64];        // running Ksum prefix

    const int b = blockIdx.x, seq = b / PPART, p = b % PPART;
    const int n0 = seq / NHEAD, h0 = seq % NHEAD;
    const int t = threadIdx.x;
    const int lane = t & 63, w = t >> 6;
    const int nn = lane & 15, qq = lane >> 4;
    const int c4 = nn << 2;
    const bool b4 = (lane >> 4) & 1, b5 = (lane >> 5) & 1;
    const int iRow = 16 * w + nn;    // this lane's query row / V^T band row

    float4 kreg[4], vreg[4];
    auto LOADKV = [&](int cc) {
        const int gb = ((n0 * LSEQ + (p * CPP + cc) * CHUNK) * NHEAD + h0) * DDIM;
#pragma unroll
        for (int rep = 0; rep < 4; ++rep) {
            const int r16 = rep * 16 + 4 * w + qq;
            kreg[rep] = *(const float4*)(kin + gb + r16 * LSTRIDE + c4);
            vreg[rep] = *(const float4*)(vin + gb + r16 * LSTRIDE + c4);
        }
    };
    auto LOADQ = [&](int cc, bf16x8& o0, bf16x8& o1) {
        const float* qp = qin + ((n0 * LSEQ + (p * CPP + cc) * CHUNK) * NHEAD + h0) * DDIM
                        + iRow * LSTRIDE;
        float4 a = phi4(*(const float4*)(qp + qq * 8));
        float4 bq = phi4(*(const float4*)(qp + qq * 8 + 4));
        float4 cq = phi4(*(const float4*)(qp + 32 + qq * 8));
        float4 dq = phi4(*(const float4*)(qp + 32 + qq * 8 + 4));
        o0 = packbf8(a, bq);
        o1 = packbf8(cq, dq);
    };

    bf16x8 qf0, qf1, qfn0, qfn1;
    LOADKV(0);
    LOADQ(0, qf0, qf1);
    if (t < 64) sKs[t] = ksws[b * DDIM + t];

    // Exclusive partition-prefix S: fp32 regs + bf16 mirror in LDS.
    const float* Sg = kvws + (size_t)b * (DDIM * DDIM);
    f32x4 Sreg[4];
#pragma unroll
    for (int ct = 0; ct < 4; ++ct) {
#pragma unroll
        for (int r = 0; r < 4; ++r) {
            const float sv = Sg[(16 * w + 4 * qq + r) * DDIM + 16 * ct + nn];
            Sreg[ct][r] = sv;
            sST[(16 * w + 4 * qq + r) * SB + 16 * ct + nn] = (short)f2bf(sv);
        }
    }

    for (int cc = 0; cc < CPP; ++cc) {
        const int gbase = ((n0 * LSEQ + (p * CPP + cc) * CHUNK) * NHEAD + h0) * DDIM;
        // ---- stage chunk into LDS (K rows + K^T + V^T) ----
#pragma unroll
        for (int rep = 0; rep < 4; ++rep) {
            const int row = rep * 16 + 4 * w + qq;
            const int l0 = rep * 16 + 4 * w;
            float4 kp = phi4(kreg[rep]);
            *(uint2*)(sK + row * SB + c4) = pack4(kp);
            float4 kt = xpose4(kp, lane);
            *(uint2*)(sKT + (c4 + qq) * SB + l0) = pack4(kt);
            float4 vt = xpose4(vreg[rep], lane);
            *(uint2*)(sVT + (c4 + qq) * SB + l0) = pack4(vt);
        }
        __syncthreads();   // S1 (orders sST/sKs updates vs reads too)

        if (cc + 1 < CPP) {   // prefetch next chunk: kreg/vreg dead once staged
            LOADKV(cc + 1);
            LOADQ(cc + 1, qfn0, qfn1);
        }

        // ---- Phase A (swapped): A^T[l][i] = mfma(Kf, Qf); lane col = iRow ----
        uint2 W[4];
        float zpart = 0.f;
#pragma unroll
        for (int ct = 0; ct < 4; ++ct) {
            bf16x8 kf0 = *(const bf16x8*)(sK + (16 * ct + nn) * SB + qq * 8);
            bf16x8 kf1 = *(const bf16x8*)(sK + (16 * ct + nn) * SB + 32 + qq * 8);
            f32x4 acc = {0.f, 0.f, 0.f, 0.f};
            acc = __builtin_amdgcn_mfma_f32_16x16x32_bf16(kf0, qf0, acc, 0, 0, 0);
            acc = __builtin_amdgcn_mfma_f32_16x16x32_bf16(kf1, qf1, acc, 0, 0, 0);
            float4 mv;
            mv.x = (16 * ct + 4 * qq + 0 <= iRow) ? acc[0] : 0.f;
            mv.y = (16 * ct + 4 * qq + 1 <= iRow) ? acc[1] : 0.f;
            mv.z = (16 * ct + 4 * qq + 2 <= iRow) ? acc[2] : 0.f;
            mv.w = (16 * ct + 4 * qq + 3 <= iRow) ? acc[3] : 0.f;
            zpart += mv.x + mv.y + mv.z + mv.w;
            W[ct] = pack4(mv);
        }
        zpart += __shfl_xor(zpart, 16);
        zpart += __shfl_xor(zpart, 32);
        float zi = zpart;
        {   // + Qf . Ksum prefix (lane-local for row iRow)
            float zq = 0.f;
#pragma unroll
            for (int j = 0; j < 8; ++j) {
                zq += bf2f(qf0[j]) * sKs[qq * 8 + j];
                zq += bf2f(qf1[j]) * sKs[32 + qq * 8 + j];
            }
            zq += __shfl_xor(zq, 16);
            zq += __shfl_xor(zq, 32);
            zi += zq;
        }

        // ---- butterfly: C-frag -> AV B-operand layout ----
        swapbit(W[0], W[1], 32, b5);
        swapbit(W[2], W[3], 32, b5);
        swapbit(W[0], W[1], 16, b4);
        swapbit(W[2], W[3], 16, b4);
        union U8 { unsigned u[4]; bf16x8 v; };
        U8 a0, a1;
        a0.u[0] = W[0].x; a0.u[1] = W[0].y; a0.u[2] = W[1].x; a0.u[3] = W[1].y;
        a1.u[0] = W[2].x; a1.u[1] = W[2].y; a1.u[2] = W[3].x; a1.u[3] = W[3].y;
        const bf16x8 amB0 = a0.v;
        const bf16x8 amB1 = a1.v;

        // ---- Phases B/C (O^T[m][i]) + KV^T accumulate ----
        f32x4 o[4] = {{0,0,0,0},{0,0,0,0},{0,0,0,0},{0,0,0,0}};
        bf16x8 av0 = *(const bf16x8*)(sVT + iRow * SB + qq * 8);
        bf16x8 av1 = *(const bf16x8*)(sVT + iRow * SB + 32 + qq * 8);
        float ksc = 0.f;
#pragma unroll
        for (int ct = 0; ct < 4; ++ct) {
            bf16x8 vf0 = *(const bf16x8*)(sVT + (16 * ct + nn) * SB + qq * 8);
            bf16x8 vf1 = *(const bf16x8*)(sVT + (16 * ct + nn) * SB + 32 + qq * 8);
            o[ct] = __builtin_amdgcn_mfma_f32_16x16x32_bf16(vf0, amB0, o[ct], 0, 0, 0);
            o[ct] = __builtin_amdgcn_mfma_f32_16x16x32_bf16(vf1, amB1, o[ct], 0, 0, 0);
            bf16x8 sf0 = *(const bf16x8*)(sST + (16 * ct + nn) * SB + qq * 8);
            bf16x8 sf1 = *(const bf16x8*)(sST + (16 * ct + nn) * SB + 32 + qq * 8);
            o[ct] = __builtin_amdgcn_mfma_f32_16x16x32_bf16(sf0, qf0, o[ct], 0, 0, 0);
            o[ct] = __builtin_amdgcn_mfma_f32_16x16x32_bf16(sf1, qf1, o[ct], 0, 0, 0);
            bf16x8 kt0 = *(const bf16x8*)(sKT + (16 * ct + nn) * SB + qq * 8);
            bf16x8 kt1 = *(const bf16x8*)(sKT + (16 * ct + nn) * SB + 32 + qq * 8);
            Sreg[ct] = __builtin_amdgcn_mfma_f32_16x16x32_bf16(av0, kt0, Sreg[ct], 0, 0, 0);
            Sreg[ct] = __builtin_amdgcn_mfma_f32_16x16x32_bf16(av1, kt1, Sreg[ct], 0, 0, 0);
            if (ct == w) {   // chunk Ksum for d-band 16w..16w+15 (d = 16w+nn)
                float s = 0.f;
#pragma unroll
                for (int j = 0; j < 8; ++j) s += bf2f(kt0[j]) + bf2f(kt1[j]);
                s += __shfl_xor(s, 16);
                s += __shfl_xor(s, 32);
                ksc = s;
            }
        }

        // ---- write final normalized out (float4 per ct) ----
        const float invz = 1.f / (zi + EPSF);
        float* orow = out + gbase + iRow * LSTRIDE;
#pragma unroll
        for (int ct = 0; ct < 4; ++ct) {
            f32x4 r = o[ct];
            r[0] *= invz; r[1] *= invz; r[2] *= invz; r[3] *= invz;
            *(f32x4*)(orow + 16 * ct + 4 * qq) = r;
        }

        __syncthreads();   // S4: all reads of sST / sVT / sKT / sK / sKs done
        if (cc + 1 < CPP) {
            // refresh bf16 S mirror + Ksum prefix for next chunk
#pragma unroll
            for (int ct = 0; ct < 4; ++ct)
#pragma unroll
                for (int r = 0; r < 4; ++r)
                    sST[(16 * w + 4 * qq + r) * SB + 16 * ct + nn] = (short)f2bf(Sreg[ct][r]);
            if (qq == 0) sKs[16 * w + nn] += ksc;
            qf0 = qfn0;
            qf1 = qfn1;
        }
    }
}

// ---------------------------------------------------------------------------
// Fallback (tiny ws): fully sequential per-sequence scan, fp32, no workspace.
// ---------------------------------------------------------------------------
__global__ __launch_bounds__(64) void k_seq(const float* __restrict__ qin,
                                            const float* __restrict__ kin,
                                            const float* __restrict__ vin,
                                            float* __restrict__ out) {
    const int seq = blockIdx.x;
    const int n = seq / NHEAD, h = seq % NHEAD;
    const int lane = threadIdx.x;
    float Scol[DDIM];
#pragma unroll
    for (int d = 0; d < DDIM; ++d) Scol[d] = 0.0f;
    float kc = 0.0f;
    __shared__ float qk[2 * DDIM];
    int base = (n * LSEQ * NHEAD + h) * DDIM + lane;
    for (int i = 0; i < LSEQ; ++i) {
        float qval = phi(qin[base]);
        float kval = phi(kin[base]);
        float vval = vin[base];
        kc += kval;
        float zp = qval * kc;
#pragma unroll
        for (int off = 32; off > 0; off >>= 1) zp += __shfl_xor(zp, off, 64);
        float z = zp + EPSF;
        qk[2 * lane] = kval;
        qk[2 * lane + 1] = qval;
        __syncthreads();
        const float4* qk4 = (const float4*)qk;
        float acc = 0.0f;
#pragma unroll
        for (int d2 = 0; d2 < DDIM / 2; ++d2) {
            float4 t0 = qk4[d2];
            int d = 2 * d2;
            Scol[d]     += t0.x * vval;  acc += t0.y * Scol[d];
            Scol[d + 1] += t0.z * vval;  acc += t0.w * Scol[d + 1];
        }
        out[base] = acc / z;
        base += LSTRIDE;
        __syncthreads();
    }
}

// ---------------------------------------------------------------------------
extern "C" void kernel_launch(void* const* d_in, const int* in_sizes, int n_in,
                              void* d_out, int out_size, void* d_ws, size_t ws_size,
                              hipStream_t stream) {
    const float* q = (const float*)d_in[0];
    const float* k = (const float*)d_in[1];
    const float* v = (const float*)d_in[2];
    float* out = (float*)d_out;
    float* ws  = (float*)d_ws;

    const size_t need = (size_t)NH * PPART * (DDIM * DDIM + DDIM) * sizeof(float);
    if (ws_size >= need) {
        float* kv   = ws;
        float* ksum = ws + (size_t)NH * PPART * DDIM * DDIM;
        k_psum <<<NH * PPART, 256, 0, stream>>>(k, v, kv, ksum);
        k_scanP<<<NH * 16,     64, 0, stream>>>(kv, ksum);
        k_fused<<<NH * PPART, 256, 0, stream>>>(q, k, v, kv, ksum, out);
    } else {
        k_seq<<<NH, 64, 0, stream>>>(q, k, v, out);
    }
}